// Round 20
// baseline (307.597 us; speedup 1.0000x reference)
//
#include <hip/hip_runtime.h>
#include <hip/hip_bf16.h>

// B=8, S=4096, D=1024, H=16, DH=64.
// R19: final GEMM re-tiled to BM=128 x BN=512 on the R14-verified 3-buf
// counted-vmcnt skeleton. Rationale: R15/R18 profiling shows the final GEMM is
// operand-REFETCH bound (512 MB staged / 96us = 5.3 TB/s; A-panel xh re-read
// 4x from L3 at BN=256). BN=512 halves A-traffic; B re-reads stay L2-resident
// (2 MB/batch slab, batch-pinned XCD). 8-phase closed (R18: correct but 110us).
// Pipeline (fp16 uniform) otherwise identical to R15.

#define B_ 8
#define S_ 4096
#define D_ 1024
#define H_ 16

typedef unsigned short u16;
typedef __attribute__((ext_vector_type(4))) short short4v;
typedef __attribute__((ext_vector_type(8))) _Float16 half8v;
typedef __attribute__((ext_vector_type(4))) float f32x4;

typedef __attribute__((address_space(3))) unsigned lds_u32_t;
typedef const __attribute__((address_space(1))) unsigned glb_u32_t;

__device__ __forceinline__ unsigned short f2h(float f) {
    _Float16 h = (_Float16)f;
    return __builtin_bit_cast(unsigned short, h);
}
__device__ __forceinline__ void gll16(const u16* g, u16* lds) {
    __builtin_amdgcn_global_load_lds((glb_u32_t*)g, (lds_u32_t*)lds, 16, 0, 0);
}
__device__ __forceinline__ void pair_decode(int pair, int& ti, int& tj) {
    ti = (int)((sqrtf(8.f * pair + 1.f) - 1.f) * 0.5f);
    if ((ti + 1) * (ti + 2) / 2 <= pair) ++ti;
    if (ti * (ti + 1) / 2 > pair) --ti;
    tj = pair - ti * (ti + 1) / 2;
}

// ---------------- Gram split-K (m97 structure, fp16) ----------------
__global__ __launch_bounds__(256) void gram_splitk(
    const u16* __restrict__ xt, float* __restrict__ P)
{
    __shared__ u16 As[128 * 32];
    __shared__ u16 Bs[128 * 32];

    const int l = ((blockIdx.x & 7) * 144) + (blockIdx.x >> 3);
    const int batch = l / 144;
    const int rem = l - batch * 144;
    const int chunk = rem / 36;
    const int pair = rem - chunk * 36;
    int ti, tj;
    pair_decode(pair, ti, tj);

    const int t = threadIdx.x, lane = t & 63, wave = t >> 6;
    const int wm = (wave >> 1) * 64, wn = (wave & 1) * 64;
    const int fr = lane & 15, kg = lane >> 4;

    const u16* Ag = xt + ((long)batch * D_ + ti * 128) * S_ + chunk * 1024;
    const u16* Bg = xt + ((long)batch * D_ + tj * 128) * S_ + chunk * 1024;

    f32x4 acc[4][4];
#pragma unroll
    for (int i = 0; i < 4; ++i)
#pragma unroll
        for (int j = 0; j < 4; ++j) acc[i][j] = (f32x4){0.f, 0.f, 0.f, 0.f};

    for (int k0 = 0; k0 < 1024; k0 += 32) {
        if (k0) __syncthreads();
#pragma unroll
        for (int r = 0; r < 2; ++r) {
            const int off = r * 2048 + t * 8;
            const int row = off >> 5, kc = off & 31;
            gll16(Ag + (long)row * S_ + k0 + kc, As + off);
            gll16(Bg + (long)row * S_ + k0 + kc, Bs + off);
        }
        __syncthreads();

        const int ao = (wm + fr) * 32 + kg * 8;
        const int bo = (wn + fr) * 32 + kg * 8;
        half8v a[4], b[4];
#pragma unroll
        for (int mt = 0; mt < 4; ++mt) a[mt] = *(const half8v*)&As[ao + mt * 512];
#pragma unroll
        for (int nt = 0; nt < 4; ++nt) b[nt] = *(const half8v*)&Bs[bo + nt * 512];
#pragma unroll
        for (int mt = 0; mt < 4; ++mt)
#pragma unroll
            for (int nt = 0; nt < 4; ++nt)
                acc[mt][nt] = __builtin_amdgcn_mfma_f32_16x16x32_f16(a[mt], b[nt], acc[mt][nt], 0, 0, 0);
    }

    float* out = P + (((long)chunk * B_ + batch) * 36 + pair) * 16384;
#pragma unroll
    for (int mt = 0; mt < 4; ++mt)
#pragma unroll
        for (int nt = 0; nt < 4; ++nt)
#pragma unroll
            for (int q = 0; q < 4; ++q)
                out[(wm + mt * 16 + kg * 4 + q) * 128 + wn + nt * 16 + fr] = acc[mt][nt][q];
}

// ---------------- reduce partials + convert + mirror (fp16 out) ----------------
__global__ __launch_bounds__(256) void reduce_mirror(
    const float* __restrict__ P, u16* __restrict__ G)
{
    __shared__ u16 th[128][132];
    const int pair = blockIdx.x, b = blockIdx.y;
    int ti, tj;
    pair_decode(pair, ti, tj);
    const int t = threadIdx.x;
    const long tile = 16384;
    const long cs = (long)B_ * 36 * tile;
    const float* base = P + ((long)b * 36 + pair) * tile;
    u16* GB = G + (long)b * D_ * D_;

#pragma unroll
    for (int e = 0; e < 16; ++e) {
        const int idx = e * 1024 + t * 4;
        float4 s0 = *(const float4*)&base[idx];
        float4 s1 = *(const float4*)&base[cs + idx];
        float4 s2 = *(const float4*)&base[2 * cs + idx];
        float4 s3 = *(const float4*)&base[3 * cs + idx];
        float f[4] = {s0.x + s1.x + s2.x + s3.x, s0.y + s1.y + s2.y + s3.y,
                      s0.z + s1.z + s2.z + s3.z, s0.w + s1.w + s2.w + s3.w};
        const int r = idx >> 7, c = idx & 127;
        short4v hv;
#pragma unroll
        for (int j = 0; j < 4; ++j) hv[j] = (short)f2h(f[j]);
        *(short4v*)&GB[(long)(ti * 128 + r) * D_ + tj * 128 + c] = hv;
        if (ti != tj) {
#pragma unroll
            for (int j = 0; j < 4; ++j) th[c + j][r] = (u16)hv[j];
        }
    }
    if (ti != tj) {
        __syncthreads();
#pragma unroll
        for (int e = 0; e < 16; ++e) {
            const int idx = e * 1024 + t * 4;
            const int r = idx >> 7, c = idx & 127;
            short4v hv = *(const short4v*)&th[r][c];
            *(short4v*)&GB[(long)(tj * 128 + r) * D_ + ti * 128 + c] = hv;
        }
    }
}

// ---------------- 256x128 3-buf counted-vmcnt GEMM (fp16) ----------------
template<int OUT>
__global__ __launch_bounds__(512) void gemm256x128(
    const u16* __restrict__ A, const u16* __restrict__ B,
    float* __restrict__ Cf, u16* __restrict__ Ch,
    int K, int lda, int ldb, int ldc, long sA, long sB, long sC)
{
    constexpr int BSZ = 12288;
    constexpr int AOF = 0, BOF = 8192;
    __shared__ u16 lds[3 * BSZ];

    const int p = blockIdx.x;
    const int l = (p & 7) * 32 + (p >> 3);
    const int bz = l >> 5;
    const int bm0 = ((l >> 3) & 3) * 256;
    const int bn0 = (l & 7) * 128;

    const int t = threadIdx.x, lane = t & 63, wave = t >> 6;
    const int wm = (wave >> 1) * 64, wn = (wave & 1) * 64;
    const int fr = lane & 15, kg = lane >> 4;
    const int xs = (fr >> 1) & 3;

    const u16* gA = A + (long)bz * sA + (long)bm0 * lda;
    const u16* gB = B + (long)bz * sB + (long)bn0 * ldb;

    f32x4 acc[4][4];
#pragma unroll
    for (int i = 0; i < 4; ++i)
#pragma unroll
        for (int j = 0; j < 4; ++j) acc[i][j] = (f32x4){0.f, 0.f, 0.f, 0.f};

    const int NT = K >> 5;

    auto stage = [&](int tt, int bs) {
        u16* base = &lds[bs * BSZ];
#pragma unroll
        for (int r = 0; r < 2; ++r) {
            const int idx = t + r * 512;
            const int row = idx >> 2, kq = idx & 3;
            const int ks = (kq ^ ((row >> 1) & 3)) << 3;
            gll16(gA + (long)row * lda + tt * 32 + ks, base + AOF + idx * 8);
        }
        {
            const int row = t >> 2, kq = t & 3;
            const int ks = (kq ^ ((row >> 1) & 3)) << 3;
            gll16(gB + (long)row * ldb + tt * 32 + ks, base + BOF + t * 8);
        }
    };

    stage(0, 0);
    stage(1, 1);
    asm volatile("s_waitcnt vmcnt(3)" ::: "memory");
    __builtin_amdgcn_s_barrier();

    for (int tt = 0; tt < NT; ++tt) {
        const u16* base = &lds[(tt % 3) * BSZ];
        if (tt + 2 < NT) stage(tt + 2, (tt + 2) % 3);

        const int ko = (kg ^ xs) << 3;
        half8v a[4], b[4];
#pragma unroll
        for (int mt = 0; mt < 4; ++mt) a[mt] = *(const half8v*)&base[AOF + (wm + mt * 16 + fr) * 32 + ko];
#pragma unroll
        for (int nt = 0; nt < 4; ++nt) b[nt] = *(const half8v*)&base[BOF + (wn + nt * 16 + fr) * 32 + ko];
#pragma unroll
        for (int mt = 0; mt < 4; ++mt)
#pragma unroll
            for (int nt = 0; nt < 4; ++nt)
                acc[mt][nt] = __builtin_amdgcn_mfma_f32_16x16x32_f16(a[mt], b[nt], acc[mt][nt], 0, 0, 0);

        if (tt + 1 < NT) {
            if (tt + 2 < NT) asm volatile("s_waitcnt vmcnt(3)" ::: "memory");
            else             asm volatile("s_waitcnt vmcnt(0)" ::: "memory");
            __builtin_amdgcn_s_barrier();
        }
    }

#pragma unroll
    for (int mt = 0; mt < 4; ++mt)
#pragma unroll
        for (int nt = 0; nt < 4; ++nt)
#pragma unroll
            for (int q = 0; q < 4; ++q) {
                const int row = bm0 + wm + mt * 16 + kg * 4 + q;
                const int col = bn0 + wn + nt * 16 + fr;
                const float v = acc[mt][nt][q];
                const long idx = (long)bz * sC + (long)row * ldc + col;
                if (OUT == 0) Cf[idx] = v;
                else Ch[idx] = f2h(v);
            }
}

// ---------------- scores + softmax via MFMA ----------------
__global__ __launch_bounds__(256) void scores_softmax_mfma(
    const u16* __restrict__ M, const u16* __restrict__ Wkh, float* __restrict__ att)
{
    constexpr int BSZ = 4096;
    constexpr int AOF = 0, BOF = 2048;
    __shared__ u16 lds[3 * BSZ];
    __shared__ float Sm[64][68];
    __shared__ float rowm[64], rowsv[64];

    const int bh = blockIdx.x;
    const int b = bh >> 4, h = bh & 15;
    const u16* gA = M + (long)b * D_ * D_ + (long)h * 64 * D_;
    const u16* gB = Wkh + (long)h * 64 * D_;

    const int t = threadIdx.x, lane = t & 63, wave = t >> 6;
    const int fr = lane & 15, kg = lane >> 4;
    const int xs = (fr >> 1) & 3;
    const int wrow = wave * 16;

    f32x4 acc[4];
#pragma unroll
    for (int i = 0; i < 4; ++i) acc[i] = (f32x4){0.f, 0.f, 0.f, 0.f};

    auto stage = [&](int tt, int bs) {
        u16* base = &lds[bs * BSZ];
        const int row = t >> 2, kq = t & 3;
        const int ks = (kq ^ ((row >> 1) & 3)) << 3;
        gll16(gA + (long)row * D_ + tt * 32 + ks, base + AOF + t * 8);
        gll16(gB + (long)row * D_ + tt * 32 + ks, base + BOF + t * 8);
    };

    stage(0, 0);
    stage(1, 1);
    asm volatile("s_waitcnt vmcnt(2)" ::: "memory");
    __builtin_amdgcn_s_barrier();

    const int NT = 32;
    for (int tt = 0; tt < NT; ++tt) {
        const u16* base = &lds[(tt % 3) * BSZ];
        if (tt + 2 < NT) stage(tt + 2, (tt + 2) % 3);

        const int ko = (kg ^ xs) << 3;
        half8v a = *(const half8v*)&base[AOF + (wrow + fr) * 32 + ko];
#pragma unroll
        for (int nt = 0; nt < 4; ++nt) {
            half8v bv = *(const half8v*)&base[BOF + (nt * 16 + fr) * 32 + ko];
            acc[nt] = __builtin_amdgcn_mfma_f32_16x16x32_f16(a, bv, acc[nt], 0, 0, 0);
        }

        if (tt + 1 < NT) {
            if (tt + 2 < NT) asm volatile("s_waitcnt vmcnt(2)" ::: "memory");
            else             asm volatile("s_waitcnt vmcnt(0)" ::: "memory");
            __builtin_amdgcn_s_barrier();
        }
    }

#pragma unroll
    for (int nt = 0; nt < 4; ++nt)
#pragma unroll
        for (int q = 0; q < 4; ++q)
            Sm[wrow + kg * 4 + q][nt * 16 + fr] = acc[nt][q] * 0.125f;
    __syncthreads();

    if (t < 64) {
        float m = -1e30f;
        for (int ee = 0; ee < 64; ++ee) m = fmaxf(m, Sm[t][ee]);
        float s = 0.f;
        for (int ee = 0; ee < 64; ++ee) s += expf(Sm[t][ee] - m);
        rowm[t] = m;
        rowsv[t] = 1.0f / s;
    }
    __syncthreads();
    float* abase = att + (long)bh * 4096;
#pragma unroll
    for (int dd = 0; dd < 16; ++dd) {
        const int d = (t >> 6) * 16 + dd;
        const int e = t & 63;
        abase[d * 64 + e] = expf(Sm[d][e] - rowm[d]) * rowsv[d];
    }
}

// ---------------- final GEMM: BM=128 x BN=512, BK=32, 3-buf counted-vmcnt ----------------
// C[m][n] = sum_k A[m][k]*B[n][k], fp16 in, fp32 out. A re-fetch = 1024/BN = 2x
// (was 4x); B re-read 32x but L2-resident (2 MB/batch, batch-per-XCD).
// 512 thr = 8 waves (2m x 4n), per-wave 64x128 (4x8 frags). LDS 3 x 40 KB.
// 5 gll16/thread/stage -> counted vmcnt(5). Same swizzle as gemm256x128.
__global__ __launch_bounds__(512) void gemm128x512(
    const u16* __restrict__ A, const u16* __restrict__ B, float* __restrict__ C,
    int K, int lda, int ldb, int ldc, long sA, long sB, long sC)
{
    constexpr int BSZ = 20480;           // shorts per slot: A 128x32 + B 512x32
    constexpr int AOF = 0, BOF = 4096;
    __shared__ u16 lds[3 * BSZ];         // 120 KiB

    const int p = blockIdx.x;
    const int l = (p & 7) * 64 + (p >> 3);   // one batch per XCD (64 blocks each)
    const int bz = l >> 6;
    const int rem = l & 63;
    const int bm0 = (rem >> 1) * 128;        // 32 m-tiles
    const int bn0 = (rem & 1) * 512;         // 2 n-tiles

    const int t = threadIdx.x, lane = t & 63, wave = t >> 6;
    const int wm = (wave >> 2) * 64;         // 2 m-groups of 64
    const int wn = (wave & 3) * 128;         // 4 n-groups of 128
    const int fr = lane & 15, kg = lane >> 4;
    const int xs = (fr >> 1) & 3;

    const u16* gA = A + (long)bz * sA + (long)bm0 * lda;
    const u16* gB = B + (long)bz * sB + (long)bn0 * ldb;

    f32x4 acc[4][8];
#pragma unroll
    for (int i = 0; i < 4; ++i)
#pragma unroll
        for (int j = 0; j < 8; ++j) acc[i][j] = (f32x4){0.f, 0.f, 0.f, 0.f};

    const int NT = K >> 5;   // 32

    auto stage = [&](int tt, int bs) {
        u16* base = &lds[bs * BSZ];
        {   // A: 128 rows x 4 chunks = 512 chunks (1/thread)
            const int row = t >> 2, kq = t & 3;
            const int ks = (kq ^ ((row >> 1) & 3)) << 3;
            gll16(gA + (long)row * lda + tt * 32 + ks, base + AOF + t * 8);
        }
#pragma unroll
        for (int r = 0; r < 4; ++r) {   // B: 512 rows x 4 chunks = 2048 chunks
            const int idx = t + r * 512;
            const int row = idx >> 2, kq = idx & 3;
            const int ks = (kq ^ ((row >> 1) & 3)) << 3;
            gll16(gB + (long)row * ldb + tt * 32 + ks, base + BOF + idx * 8);
        }
    };

    stage(0, 0);
    stage(1, 1);
    asm volatile("s_waitcnt vmcnt(5)" ::: "memory");
    __builtin_amdgcn_s_barrier();

    for (int tt = 0; tt < NT; ++tt) {
        const u16* base = &lds[(tt % 3) * BSZ];
        if (tt + 2 < NT) stage(tt + 2, (tt + 2) % 3);

        const int ko = (kg ^ xs) << 3;
        half8v a[4], b[8];
#pragma unroll
        for (int mt = 0; mt < 4; ++mt) a[mt] = *(const half8v*)&base[AOF + (wm + mt * 16 + fr) * 32 + ko];
#pragma unroll
        for (int nt = 0; nt < 8; ++nt) b[nt] = *(const half8v*)&base[BOF + (wn + nt * 16 + fr) * 32 + ko];
        __builtin_amdgcn_s_setprio(1);
#pragma unroll
        for (int mt = 0; mt < 4; ++mt)
#pragma unroll
            for (int nt = 0; nt < 8; ++nt)
                acc[mt][nt] = __builtin_amdgcn_mfma_f32_16x16x32_f16(a[mt], b[nt], acc[mt][nt], 0, 0, 0);
        __builtin_amdgcn_s_setprio(0);

        if (tt + 1 < NT) {
            if (tt + 2 < NT) asm volatile("s_waitcnt vmcnt(5)" ::: "memory");
            else             asm volatile("s_waitcnt vmcnt(0)" ::: "memory");
            __builtin_amdgcn_s_barrier();
        }
    }

    // C/D layout (m89): col = fr, row = kg*4+q within frag. Plain stores.
#pragma unroll
    for (int mt = 0; mt < 4; ++mt)
#pragma unroll
        for (int nt = 0; nt < 8; ++nt)
#pragma unroll
            for (int q = 0; q < 4; ++q) {
                const int row = bm0 + wm + mt * 16 + kg * 4 + q;
                const int col = bn0 + wn + nt * 16 + fr;
                C[(long)bz * sC + (long)row * ldc + col] = acc[mt][nt][q];
            }
}

// ---------------- prepack: x -> xt fp16 [D][S] + xh fp16 [S][D] ----------------
__global__ __launch_bounds__(256) void prepack_xt(
    const float* __restrict__ x, u16* __restrict__ xt, u16* __restrict__ xh)
{
    __shared__ float tile[64][65];
    const int d0 = blockIdx.x * 64, s0 = blockIdx.y * 64, b = blockIdx.z;
    const float* xb = x + (long)b * S_ * D_;
    const int t = threadIdx.x;
    const int sr = t >> 4, dc = (t & 15) * 4;
#pragma unroll
    for (int r = 0; r < 4; ++r) {
        const int s = sr + r * 16;
        float4 v = *(const float4*)&xb[(long)(s0 + s) * D_ + d0 + dc];
        tile[dc + 0][s] = v.x;
        tile[dc + 1][s] = v.y;
        tile[dc + 2][s] = v.z;
        tile[dc + 3][s] = v.w;
        short4v hv = {(short)f2h(v.x), (short)f2h(v.y), (short)f2h(v.z), (short)f2h(v.w)};
        *(short4v*)&xh[((long)b * S_ + s0 + s) * D_ + d0 + dc] = hv;
    }
    __syncthreads();
    const int dr = t >> 4, sc = (t & 15) * 4;
    u16* tb = xt + (long)b * D_ * S_;
#pragma unroll
    for (int r = 0; r < 4; ++r) {
        const int d = dr + r * 16;
        short4v hv;
#pragma unroll
        for (int j = 0; j < 4; ++j) hv[j] = (short)f2h(tile[d][sc + j]);
        *(short4v*)&tb[(long)(d0 + d) * S_ + s0 + sc] = hv;
    }
}

// ---------------- weight converts: Wq + Wk + Wo -> fp16 ----------------
__global__ __launch_bounds__(256) void convert_w(
    const float* __restrict__ Wq, const float* __restrict__ Wk, const float* __restrict__ Wo,
    u16* __restrict__ Wqh, u16* __restrict__ Wkh, u16* __restrict__ Woh)
{
    const int blk = blockIdx.x;
    const float* src;
    u16* dst;
    if (blk < 1024)      { src = Wq; dst = Wqh; }
    else if (blk < 2048) { src = Wk; dst = Wkh; }
    else                 { src = Wo; dst = Woh; }
    const long i = ((long)(blk & 1023) * 256 + threadIdx.x) * 4;
    float4 v = *(const float4*)&src[i];
    short4v hv = {(short)f2h(v.x), (short)f2h(v.y), (short)f2h(v.z), (short)f2h(v.w)};
    *(short4v*)&dst[i] = hv;
}

// ---------------- T build (fp32 compute, fp16 out) ----------------
__global__ __launch_bounds__(256) void build_T(
    const float* __restrict__ Wv, const float* __restrict__ att, u16* __restrict__ T)
{
    __shared__ float atts[64][65];
    __shared__ float Wvs[64][65];
    const int i0 = blockIdx.x * 64, h = blockIdx.y, b = blockIdx.z;
    const int t = threadIdx.x;
    {
        int row = t >> 2, c4 = (t & 3) * 16;
        const float* ab = att + (((long)b * H_ + h) * 64) * 64;
        const float* wb = Wv + (long)h * 64 * D_ + i0;
#pragma unroll
        for (int r = 0; r < 4; ++r) {
            float4 v = *(const float4*)&ab[row * 64 + c4 + r * 4];
            atts[row][c4 + r * 4 + 0] = v.x;
            atts[row][c4 + r * 4 + 1] = v.y;
            atts[row][c4 + r * 4 + 2] = v.z;
            atts[row][c4 + r * 4 + 3] = v.w;
            float4 w = *(const float4*)&wb[(long)row * D_ + c4 + r * 4];
            Wvs[row][c4 + r * 4 + 0] = w.x;
            Wvs[row][c4 + r * 4 + 1] = w.y;
            Wvs[row][c4 + r * 4 + 2] = w.z;
            Wvs[row][c4 + r * 4 + 3] = w.w;
        }
    }
    __syncthreads();
    const int e = t & 63, ig = t >> 6;
    float acc[16];
#pragma unroll
    for (int i = 0; i < 16; ++i) acc[i] = 0.f;
#pragma unroll 8
    for (int d = 0; d < 64; ++d) {
        float av = atts[d][e];
#pragma unroll
        for (int ii = 0; ii < 16; ++ii)
            acc[ii] = fmaf(Wvs[d][ig * 16 + ii], av, acc[ii]);
    }
    u16* Tb = T + (long)b * D_ * D_;
#pragma unroll
    for (int ii = 0; ii < 16; ++ii) {
        int i = i0 + ig * 16 + ii;
        Tb[(long)i * D_ + h * 64 + e] = f2h(acc[ii]);
    }
}

extern "C" void kernel_launch(void* const* d_in, const int* in_sizes, int n_in,
                              void* d_out, int out_size, void* d_ws, size_t ws_size,
                              hipStream_t stream) {
    const float* x  = (const float*)d_in[0];
    const float* Wq = (const float*)d_in[1];
    const float* Wk = (const float*)d_in[2];
    const float* Wv = (const float*)d_in[3];
    const float* Wo = (const float*)d_in[4];
    float* out = (float*)d_out;

    const long MM = (long)D_ * D_;          // 1,048,576
    const long XE = (long)B_ * S_ * D_;     // 33,554,432
    const long GE = (long)B_ * MM;          // 8,388,608
    const long PB = 4L * B_ * 36 * 16384 * 4;  // 75,497,472 bytes

    u16* xt = (u16*)d_out;                  // fp16 [B][D][S]; dead before final GEMM

    // ws layout = exactly 184,549,376 B (proven available since R6):
    // xh | P(75.5; M fp16 aliases after reduce) | G | Eth | att | Wqh | Woh | Wkh
    char* w = (char*)d_ws;
    u16* xh    = (u16*)w;   w += XE * 2;
    float* P   = (float*)w;
    u16* Mh    = (u16*)w;   w += PB;
    u16* G     = (u16*)w;   w += GE * 2;
    u16* Eth   = (u16*)w;   w += GE * 2;
    float* att = (float*)w; w += (long)B_ * H_ * 64 * 64 * 4;
    u16* Wqh   = (u16*)w;   w += MM * 2;
    u16* Woh   = (u16*)w;   w += MM * 2;
    u16* Wkh   = (u16*)w;
    u16* Th = G;

    // 1. prepacks
    prepack_xt<<<dim3(D_ / 64, S_ / 64, B_), 256, 0, stream>>>(x, xt, xh);
    convert_w<<<3072, 256, 0, stream>>>(Wq, Wk, Wo, Wqh, Wkh, Woh);

    // 2. Gram split-K -> P (fp16, m97 structure)
    gram_splitk<<<36 * 4 * B_, 256, 0, stream>>>(xt, P);

    // 3. reduce + mirror -> G fp16
    reduce_mirror<<<dim3(36, B_), 256, 0, stream>>>(P, G);

    // 4. M[i][j] = sum_k Wq[i,k] G[j,k]  -> fp16 (aliases P; P dead)
    gemm256x128<1><<<256, 512, 0, stream>>>(
        Wqh, G, nullptr, Mh, D_, D_, D_, D_, 0, MM, MM);

    // 5. scores + softmax (MFMA) -> att fp32
    scores_softmax_mfma<<<B_ * H_, 256, 0, stream>>>(Mh, Wkh, att);

    // 6. T (fp16) -> Th (aliases G; G consumed)
    build_T<<<dim3(D_ / 64, H_, B_), 256, 0, stream>>>(Wv, att, Th);

    // 7. Et[j][i] = sum_k Wo[j][k] T[i][k] -> fp16
    gemm256x128<1><<<256, 512, 0, stream>>>(
        Woh, Th, nullptr, Eth, D_, D_, D_, D_, 0, MM, MM);

    // 8. out[s][j] = sum_i x[s][i] Et[j][i]  -- 128x512 tile, 3-buf counted
    gemm128x512<<<(S_ / 128) * (D_ / 512) * B_, 512, 0, stream>>>(
        xh, Eth, out, D_, D_, D_, D_, (long)S_ * D_, MM, (long)S_ * D_);
}

// Round 21
// 297.479 us; speedup vs baseline: 1.0340x; 1.0340x over previous
//
#include <hip/hip_runtime.h>
#include <hip/hip_bf16.h>

// B=8, S=4096, D=1024, H=16, DH=64.
// R20: final GEMM reverted to R15's BK=64 2-slot (best measured, 96.6us;
// coarse-schedule floor per 4-structure sweep R14/R15/R18/R19).
// NEW: P partials stored fp16 (halves gram-write + reduce-read traffic);
// convert_w fused into prepack (one fewer launch).
// Pipeline (fp16 uniform):
//   prepack_all: x -> xt [B][D][S] + xh [B][S][D] fp16; Wq/Wk/Wo -> fp16
//   gram: G-chunk partials (lower-tri, SPLIT-K=4) -> P fp16
//   reduce_mirror: P -> G fp16 (symmetric)
//   M = Wq x G-rows [256x128 3-buf] -> fp16 (aliases P)
//   scores/softmax MFMA -> att fp32 ; T build -> fp16 (aliases G)
//   Et = Wo x T-rows [256x128] -> fp16
//   out = x @ E [256^2 BK=64 2-slot + setprio] -> fp32

#define B_ 8
#define S_ 4096
#define D_ 1024
#define H_ 16

typedef unsigned short u16;
typedef __attribute__((ext_vector_type(4))) short short4v;
typedef __attribute__((ext_vector_type(8))) _Float16 half8v;
typedef __attribute__((ext_vector_type(4))) float f32x4;

typedef __attribute__((address_space(3))) unsigned lds_u32_t;
typedef const __attribute__((address_space(1))) unsigned glb_u32_t;

__device__ __forceinline__ unsigned short f2h(float f) {
    _Float16 h = (_Float16)f;
    return __builtin_bit_cast(unsigned short, h);
}
__device__ __forceinline__ float h2f(unsigned short s) {
    return (float)__builtin_bit_cast(_Float16, s);
}
__device__ __forceinline__ void gll16(const u16* g, u16* lds) {
    __builtin_amdgcn_global_load_lds((glb_u32_t*)g, (lds_u32_t*)lds, 16, 0, 0);
}
__device__ __forceinline__ void pair_decode(int pair, int& ti, int& tj) {
    ti = (int)((sqrtf(8.f * pair + 1.f) - 1.f) * 0.5f);
    if ((ti + 1) * (ti + 2) / 2 <= pair) ++ti;
    if (ti * (ti + 1) / 2 > pair) --ti;
    tj = pair - ti * (ti + 1) / 2;
}

// ---------------- Gram split-K (m97 structure, fp16 in, fp16 partials out) ----------------
__global__ __launch_bounds__(256) void gram_splitk(
    const u16* __restrict__ xt, u16* __restrict__ P)
{
    __shared__ u16 As[128 * 32];
    __shared__ u16 Bs[128 * 32];

    const int l = ((blockIdx.x & 7) * 144) + (blockIdx.x >> 3);
    const int batch = l / 144;
    const int rem = l - batch * 144;
    const int chunk = rem / 36;
    const int pair = rem - chunk * 36;
    int ti, tj;
    pair_decode(pair, ti, tj);

    const int t = threadIdx.x, lane = t & 63, wave = t >> 6;
    const int wm = (wave >> 1) * 64, wn = (wave & 1) * 64;
    const int fr = lane & 15, kg = lane >> 4;

    const u16* Ag = xt + ((long)batch * D_ + ti * 128) * S_ + chunk * 1024;
    const u16* Bg = xt + ((long)batch * D_ + tj * 128) * S_ + chunk * 1024;

    f32x4 acc[4][4];
#pragma unroll
    for (int i = 0; i < 4; ++i)
#pragma unroll
        for (int j = 0; j < 4; ++j) acc[i][j] = (f32x4){0.f, 0.f, 0.f, 0.f};

    for (int k0 = 0; k0 < 1024; k0 += 32) {
        if (k0) __syncthreads();
#pragma unroll
        for (int r = 0; r < 2; ++r) {
            const int off = r * 2048 + t * 8;
            const int row = off >> 5, kc = off & 31;
            gll16(Ag + (long)row * S_ + k0 + kc, As + off);
            gll16(Bg + (long)row * S_ + k0 + kc, Bs + off);
        }
        __syncthreads();

        const int ao = (wm + fr) * 32 + kg * 8;
        const int bo = (wn + fr) * 32 + kg * 8;
        half8v a[4], b[4];
#pragma unroll
        for (int mt = 0; mt < 4; ++mt) a[mt] = *(const half8v*)&As[ao + mt * 512];
#pragma unroll
        for (int nt = 0; nt < 4; ++nt) b[nt] = *(const half8v*)&Bs[bo + nt * 512];
#pragma unroll
        for (int mt = 0; mt < 4; ++mt)
#pragma unroll
            for (int nt = 0; nt < 4; ++nt)
                acc[mt][nt] = __builtin_amdgcn_mfma_f32_16x16x32_f16(a[mt], b[nt], acc[mt][nt], 0, 0, 0);
    }

    u16* out = P + (((long)chunk * B_ + batch) * 36 + pair) * 16384;
#pragma unroll
    for (int mt = 0; mt < 4; ++mt)
#pragma unroll
        for (int nt = 0; nt < 4; ++nt)
#pragma unroll
            for (int q = 0; q < 4; ++q)
                out[(wm + mt * 16 + kg * 4 + q) * 128 + wn + nt * 16 + fr] = f2h(acc[mt][nt][q]);
}

// ---------------- reduce fp16 partials + mirror (fp16 out) ----------------
__global__ __launch_bounds__(256) void reduce_mirror(
    const u16* __restrict__ P, u16* __restrict__ G)
{
    __shared__ u16 th[128][132];
    const int pair = blockIdx.x, b = blockIdx.y;
    int ti, tj;
    pair_decode(pair, ti, tj);
    const int t = threadIdx.x;
    const long tile = 16384;
    const long cs = (long)B_ * 36 * tile;
    const u16* base = P + ((long)b * 36 + pair) * tile;
    u16* GB = G + (long)b * D_ * D_;

#pragma unroll
    for (int e = 0; e < 16; ++e) {
        const int idx = e * 1024 + t * 4;
        short4v s0 = *(const short4v*)&base[idx];
        short4v s1 = *(const short4v*)&base[cs + idx];
        short4v s2 = *(const short4v*)&base[2 * cs + idx];
        short4v s3 = *(const short4v*)&base[3 * cs + idx];
        const int r = idx >> 7, c = idx & 127;
        short4v hv;
#pragma unroll
        for (int j = 0; j < 4; ++j) {
            const float f = h2f((u16)s0[j]) + h2f((u16)s1[j]) + h2f((u16)s2[j]) + h2f((u16)s3[j]);
            hv[j] = (short)f2h(f);
        }
        *(short4v*)&GB[(long)(ti * 128 + r) * D_ + tj * 128 + c] = hv;
        if (ti != tj) {
#pragma unroll
            for (int j = 0; j < 4; ++j) th[c + j][r] = (u16)hv[j];
        }
    }
    if (ti != tj) {
        __syncthreads();
#pragma unroll
        for (int e = 0; e < 16; ++e) {
            const int idx = e * 1024 + t * 4;
            const int r = idx >> 7, c = idx & 127;
            short4v hv = *(const short4v*)&th[r][c];
            *(short4v*)&GB[(long)(tj * 128 + r) * D_ + ti * 128 + c] = hv;
        }
    }
}

// ---------------- 256x128 3-buf counted-vmcnt GEMM (fp16) ----------------
template<int OUT>
__global__ __launch_bounds__(512) void gemm256x128(
    const u16* __restrict__ A, const u16* __restrict__ B,
    float* __restrict__ Cf, u16* __restrict__ Ch,
    int K, int lda, int ldb, int ldc, long sA, long sB, long sC)
{
    constexpr int BSZ = 12288;
    constexpr int AOF = 0, BOF = 8192;
    __shared__ u16 lds[3 * BSZ];

    const int p = blockIdx.x;
    const int l = (p & 7) * 32 + (p >> 3);
    const int bz = l >> 5;
    const int bm0 = ((l >> 3) & 3) * 256;
    const int bn0 = (l & 7) * 128;

    const int t = threadIdx.x, lane = t & 63, wave = t >> 6;
    const int wm = (wave >> 1) * 64, wn = (wave & 1) * 64;
    const int fr = lane & 15, kg = lane >> 4;
    const int xs = (fr >> 1) & 3;

    const u16* gA = A + (long)bz * sA + (long)bm0 * lda;
    const u16* gB = B + (long)bz * sB + (long)bn0 * ldb;

    f32x4 acc[4][4];
#pragma unroll
    for (int i = 0; i < 4; ++i)
#pragma unroll
        for (int j = 0; j < 4; ++j) acc[i][j] = (f32x4){0.f, 0.f, 0.f, 0.f};

    const int NT = K >> 5;

    auto stage = [&](int tt, int bs) {
        u16* base = &lds[bs * BSZ];
#pragma unroll
        for (int r = 0; r < 2; ++r) {
            const int idx = t + r * 512;
            const int row = idx >> 2, kq = idx & 3;
            const int ks = (kq ^ ((row >> 1) & 3)) << 3;
            gll16(gA + (long)row * lda + tt * 32 + ks, base + AOF + idx * 8);
        }
        {
            const int row = t >> 2, kq = t & 3;
            const int ks = (kq ^ ((row >> 1) & 3)) << 3;
            gll16(gB + (long)row * ldb + tt * 32 + ks, base + BOF + t * 8);
        }
    };

    stage(0, 0);
    stage(1, 1);
    asm volatile("s_waitcnt vmcnt(3)" ::: "memory");
    __builtin_amdgcn_s_barrier();

    for (int tt = 0; tt < NT; ++tt) {
        const u16* base = &lds[(tt % 3) * BSZ];
        if (tt + 2 < NT) stage(tt + 2, (tt + 2) % 3);

        const int ko = (kg ^ xs) << 3;
        half8v a[4], b[4];
#pragma unroll
        for (int mt = 0; mt < 4; ++mt) a[mt] = *(const half8v*)&base[AOF + (wm + mt * 16 + fr) * 32 + ko];
#pragma unroll
        for (int nt = 0; nt < 4; ++nt) b[nt] = *(const half8v*)&base[BOF + (wn + nt * 16 + fr) * 32 + ko];
#pragma unroll
        for (int mt = 0; mt < 4; ++mt)
#pragma unroll
            for (int nt = 0; nt < 4; ++nt)
                acc[mt][nt] = __builtin_amdgcn_mfma_f32_16x16x32_f16(a[mt], b[nt], acc[mt][nt], 0, 0, 0);

        if (tt + 1 < NT) {
            if (tt + 2 < NT) asm volatile("s_waitcnt vmcnt(3)" ::: "memory");
            else             asm volatile("s_waitcnt vmcnt(0)" ::: "memory");
            __builtin_amdgcn_s_barrier();
        }
    }

#pragma unroll
    for (int mt = 0; mt < 4; ++mt)
#pragma unroll
        for (int nt = 0; nt < 4; ++nt)
#pragma unroll
            for (int q = 0; q < 4; ++q) {
                const int row = bm0 + wm + mt * 16 + kg * 4 + q;
                const int col = bn0 + wn + nt * 16 + fr;
                const float v = acc[mt][nt][q];
                const long idx = (long)bz * sC + (long)row * ldc + col;
                if (OUT == 0) Cf[idx] = v;
                else Ch[idx] = f2h(v);
            }
}

// ---------------- scores + softmax via MFMA ----------------
__global__ __launch_bounds__(256) void scores_softmax_mfma(
    const u16* __restrict__ M, const u16* __restrict__ Wkh, float* __restrict__ att)
{
    constexpr int BSZ = 4096;
    constexpr int AOF = 0, BOF = 2048;
    __shared__ u16 lds[3 * BSZ];
    __shared__ float Sm[64][68];
    __shared__ float rowm[64], rowsv[64];

    const int bh = blockIdx.x;
    const int b = bh >> 4, h = bh & 15;
    const u16* gA = M + (long)b * D_ * D_ + (long)h * 64 * D_;
    const u16* gB = Wkh + (long)h * 64 * D_;

    const int t = threadIdx.x, lane = t & 63, wave = t >> 6;
    const int fr = lane & 15, kg = lane >> 4;
    const int xs = (fr >> 1) & 3;
    const int wrow = wave * 16;

    f32x4 acc[4];
#pragma unroll
    for (int i = 0; i < 4; ++i) acc[i] = (f32x4){0.f, 0.f, 0.f, 0.f};

    auto stage = [&](int tt, int bs) {
        u16* base = &lds[bs * BSZ];
        const int row = t >> 2, kq = t & 3;
        const int ks = (kq ^ ((row >> 1) & 3)) << 3;
        gll16(gA + (long)row * D_ + tt * 32 + ks, base + AOF + t * 8);
        gll16(gB + (long)row * D_ + tt * 32 + ks, base + BOF + t * 8);
    };

    stage(0, 0);
    stage(1, 1);
    asm volatile("s_waitcnt vmcnt(2)" ::: "memory");
    __builtin_amdgcn_s_barrier();

    const int NT = 32;
    for (int tt = 0; tt < NT; ++tt) {
        const u16* base = &lds[(tt % 3) * BSZ];
        if (tt + 2 < NT) stage(tt + 2, (tt + 2) % 3);

        const int ko = (kg ^ xs) << 3;
        half8v a = *(const half8v*)&base[AOF + (wrow + fr) * 32 + ko];
#pragma unroll
        for (int nt = 0; nt < 4; ++nt) {
            half8v bv = *(const half8v*)&base[BOF + (nt * 16 + fr) * 32 + ko];
            acc[nt] = __builtin_amdgcn_mfma_f32_16x16x32_f16(a, bv, acc[nt], 0, 0, 0);
        }

        if (tt + 1 < NT) {
            if (tt + 2 < NT) asm volatile("s_waitcnt vmcnt(2)" ::: "memory");
            else             asm volatile("s_waitcnt vmcnt(0)" ::: "memory");
            __builtin_amdgcn_s_barrier();
        }
    }

#pragma unroll
    for (int nt = 0; nt < 4; ++nt)
#pragma unroll
        for (int q = 0; q < 4; ++q)
            Sm[wrow + kg * 4 + q][nt * 16 + fr] = acc[nt][q] * 0.125f;
    __syncthreads();

    if (t < 64) {
        float m = -1e30f;
        for (int ee = 0; ee < 64; ++ee) m = fmaxf(m, Sm[t][ee]);
        float s = 0.f;
        for (int ee = 0; ee < 64; ++ee) s += expf(Sm[t][ee] - m);
        rowm[t] = m;
        rowsv[t] = 1.0f / s;
    }
    __syncthreads();
    float* abase = att + (long)bh * 4096;
#pragma unroll
    for (int dd = 0; dd < 16; ++dd) {
        const int d = (t >> 6) * 16 + dd;
        const int e = t & 63;
        abase[d * 64 + e] = expf(Sm[d][e] - rowm[d]) * rowsv[d];
    }
}

// ---------------- final GEMM: 256^2, BK=64, 2-slot stage-at-iter-start ----------------
// R15-verified structure (best of 4 variants: 96.6us). Plain stores.
__global__ __launch_bounds__(512) void gemm256_f16(
    const u16* __restrict__ A, const u16* __restrict__ B, float* __restrict__ C,
    int K, int lda, int ldb, int ldc, long sA, long sB, long sC)
{
    __shared__ u16 lds[2][2][256 * 64];   // 128 KiB

    const int p = blockIdx.x;
    const int l = (p & 7) * 64 + (p >> 3);   // one batch per XCD
    const int bz = l >> 6;
    const int bm0 = ((l >> 2) & 15) * 256;
    const int bn0 = (l & 3) * 256;

    const int t = threadIdx.x, lane = t & 63, wave = t >> 6;
    const int wm = (wave >> 2) * 128, wn = (wave & 3) * 64;
    const int fr = lane & 15, kg = lane >> 4;

    const u16* Ag = A + (long)bz * sA + (long)bm0 * lda;
    const u16* Bg = B + (long)bz * sB + (long)bn0 * ldb;

    f32x4 acc[8][4];
#pragma unroll
    for (int i = 0; i < 8; ++i)
#pragma unroll
        for (int j = 0; j < 4; ++j) acc[i][j] = (f32x4){0.f, 0.f, 0.f, 0.f};

    const int NT = K >> 6;   // 16

    auto stage = [&](int tt, int s) {
#pragma unroll
        for (int c = 0; c < 4; ++c) {
            const int idx = t + c * 512;       // 0..2047 16B chunks
            const int row = idx >> 3;          // 0..255
            const int kq = idx & 7;
            const int ks = (kq ^ ((row >> 1) & 7)) << 3;   // inverse swizzle (shorts)
            gll16(Ag + (long)row * lda + tt * 64 + ks, &lds[s][0][idx * 8]);
            gll16(Bg + (long)row * ldb + tt * 64 + ks, &lds[s][1][idx * 8]);
        }
    };

    stage(0, 0);
    asm volatile("s_waitcnt vmcnt(0)" ::: "memory");
    __builtin_amdgcn_s_barrier();

    for (int tt = 0; tt < NT; ++tt) {
        const int cur = tt & 1;
        if (tt + 1 < NT) stage(tt + 1, cur ^ 1);

        const u16* As = &lds[cur][0][0];
        const u16* Bs = &lds[cur][1][0];

        __builtin_amdgcn_s_setprio(1);
#pragma unroll
        for (int ks2 = 0; ks2 < 2; ++ks2) {
            half8v bf[4];
#pragma unroll
            for (int nt = 0; nt < 4; ++nt) {
                const int row = wn + nt * 16 + fr;
                const int off = row * 64 + (((ks2 * 4 + kg) ^ ((row >> 1) & 7)) << 3);
                bf[nt] = *(const half8v*)&Bs[off];
            }
#pragma unroll
            for (int mt = 0; mt < 8; ++mt) {
                const int row = wm + mt * 16 + fr;
                const int off = row * 64 + (((ks2 * 4 + kg) ^ ((row >> 1) & 7)) << 3);
                half8v af = *(const half8v*)&As[off];
#pragma unroll
                for (int nt = 0; nt < 4; ++nt)
                    acc[mt][nt] = __builtin_amdgcn_mfma_f32_16x16x32_f16(af, bf[nt], acc[mt][nt], 0, 0, 0);
            }
        }
        __builtin_amdgcn_s_setprio(0);

        asm volatile("s_waitcnt vmcnt(0)" ::: "memory");
        __builtin_amdgcn_s_barrier();
    }

#pragma unroll
    for (int mt = 0; mt < 8; ++mt)
#pragma unroll
        for (int nt = 0; nt < 4; ++nt)
#pragma unroll
            for (int q = 0; q < 4; ++q) {
                const int row = bm0 + wm + mt * 16 + kg * 4 + q;
                const int col = bn0 + wn + nt * 16 + fr;
                C[(long)bz * sC + (long)row * ldc + col] = acc[mt][nt][q];
            }
}

// ---------------- fused prepack: x tiles + weight converts (1-D grid) ----------------
// blocks 0..8191: 64x64 x-tile -> xt (transposed) + xh (row-major), fp16.
// blocks 8192..11263: Wq/Wk/Wo fp32 -> fp16 (1024 blocks each).
__global__ __launch_bounds__(256) void prepack_all(
    const float* __restrict__ x, u16* __restrict__ xt, u16* __restrict__ xh,
    const float* __restrict__ Wq, const float* __restrict__ Wk, const float* __restrict__ Wo,
    u16* __restrict__ Wqh, u16* __restrict__ Wkh, u16* __restrict__ Woh)
{
    const int bid = blockIdx.x;
    const int t = threadIdx.x;
    if (bid >= 8192) {
        const int wb = bid - 8192;
        const float* src;
        u16* dst;
        if (wb < 1024)      { src = Wq; dst = Wqh; }
        else if (wb < 2048) { src = Wk; dst = Wkh; }
        else                { src = Wo; dst = Woh; }
        const long i = ((long)(wb & 1023) * 256 + t) * 4;
        float4 v = *(const float4*)&src[i];
        short4v hv = {(short)f2h(v.x), (short)f2h(v.y), (short)f2h(v.z), (short)f2h(v.w)};
        *(short4v*)&dst[i] = hv;
        return;
    }

    __shared__ float tile[64][65];
    const int d0 = (bid & 15) * 64;
    const int s0 = ((bid >> 4) & 63) * 64;
    const int b = bid >> 10;
    const float* xb = x + (long)b * S_ * D_;
    const int sr = t >> 4, dc = (t & 15) * 4;
#pragma unroll
    for (int r = 0; r < 4; ++r) {
        const int s = sr + r * 16;
        float4 v = *(const float4*)&xb[(long)(s0 + s) * D_ + d0 + dc];
        tile[dc + 0][s] = v.x;
        tile[dc + 1][s] = v.y;
        tile[dc + 2][s] = v.z;
        tile[dc + 3][s] = v.w;
        short4v hv = {(short)f2h(v.x), (short)f2h(v.y), (short)f2h(v.z), (short)f2h(v.w)};
        *(short4v*)&xh[((long)b * S_ + s0 + s) * D_ + d0 + dc] = hv;
    }
    __syncthreads();
    const int dr = t >> 4, sc = (t & 15) * 4;
    u16* tb = xt + (long)b * D_ * S_;
#pragma unroll
    for (int r = 0; r < 4; ++r) {
        const int d = dr + r * 16;
        short4v hv;
#pragma unroll
        for (int j = 0; j < 4; ++j) hv[j] = (short)f2h(tile[d][sc + j]);
        *(short4v*)&tb[(long)(d0 + d) * S_ + s0 + sc] = hv;
    }
}

// ---------------- T build (fp32 compute, fp16 out) ----------------
__global__ __launch_bounds__(256) void build_T(
    const float* __restrict__ Wv, const float* __restrict__ att, u16* __restrict__ T)
{
    __shared__ float atts[64][65];
    __shared__ float Wvs[64][65];
    const int i0 = blockIdx.x * 64, h = blockIdx.y, b = blockIdx.z;
    const int t = threadIdx.x;
    {
        int row = t >> 2, c4 = (t & 3) * 16;
        const float* ab = att + (((long)b * H_ + h) * 64) * 64;
        const float* wb = Wv + (long)h * 64 * D_ + i0;
#pragma unroll
        for (int r = 0; r < 4; ++r) {
            float4 v = *(const float4*)&ab[row * 64 + c4 + r * 4];
            atts[row][c4 + r * 4 + 0] = v.x;
            atts[row][c4 + r * 4 + 1] = v.y;
            atts[row][c4 + r * 4 + 2] = v.z;
            atts[row][c4 + r * 4 + 3] = v.w;
            float4 w = *(const float4*)&wb[(long)row * D_ + c4 + r * 4];
            Wvs[row][c4 + r * 4 + 0] = w.x;
            Wvs[row][c4 + r * 4 + 1] = w.y;
            Wvs[row][c4 + r * 4 + 2] = w.z;
            Wvs[row][c4 + r * 4 + 3] = w.w;
        }
    }
    __syncthreads();
    const int e = t & 63, ig = t >> 6;
    float acc[16];
#pragma unroll
    for (int i = 0; i < 16; ++i) acc[i] = 0.f;
#pragma unroll 8
    for (int d = 0; d < 64; ++d) {
        float av = atts[d][e];
#pragma unroll
        for (int ii = 0; ii < 16; ++ii)
            acc[ii] = fmaf(Wvs[d][ig * 16 + ii], av, acc[ii]);
    }
    u16* Tb = T + (long)b * D_ * D_;
#pragma unroll
    for (int ii = 0; ii < 16; ++ii) {
        int i = i0 + ig * 16 + ii;
        Tb[(long)i * D_ + h * 64 + e] = f2h(acc[ii]);
    }
}

extern "C" void kernel_launch(void* const* d_in, const int* in_sizes, int n_in,
                              void* d_out, int out_size, void* d_ws, size_t ws_size,
                              hipStream_t stream) {
    const float* x  = (const float*)d_in[0];
    const float* Wq = (const float*)d_in[1];
    const float* Wk = (const float*)d_in[2];
    const float* Wv = (const float*)d_in[3];
    const float* Wo = (const float*)d_in[4];
    float* out = (float*)d_out;

    const long MM = (long)D_ * D_;          // 1,048,576
    const long XE = (long)B_ * S_ * D_;     // 33,554,432
    const long GE = (long)B_ * MM;          // 8,388,608
    const long PB = 4L * B_ * 36 * 16384 * 4;  // region reserved (P fp16 uses half)

    u16* xt = (u16*)d_out;                  // fp16 [B][D][S]; dead before final GEMM

    // ws layout = exactly 184,549,376 B (proven available since R6):
    // xh | P-region(75.5 reserved; P fp16 uses 37.7, M fp16 aliases) | G | Eth |
    // att | Wqh | Woh | Wkh
    char* w = (char*)d_ws;
    u16* xh    = (u16*)w;   w += XE * 2;
    u16* P     = (u16*)w;
    u16* Mh    = (u16*)w;   w += PB;
    u16* G     = (u16*)w;   w += GE * 2;
    u16* Eth   = (u16*)w;   w += GE * 2;
    float* att = (float*)w; w += (long)B_ * H_ * 64 * 64 * 4;
    u16* Wqh   = (u16*)w;   w += MM * 2;
    u16* Woh   = (u16*)w;   w += MM * 2;
    u16* Wkh   = (u16*)w;
    u16* Th = G;

    // 1. fused prepack (x tiles + 3 weight converts)
    prepack_all<<<8192 + 3072, 256, 0, stream>>>(
        x, xt, xh, Wq, Wk, Wo, Wqh, Wkh, Woh);

    // 2. Gram split-K -> P fp16 (m97 structure)
    gram_splitk<<<36 * 4 * B_, 256, 0, stream>>>(xt, P);

    // 3. reduce + mirror -> G fp16
    reduce_mirror<<<dim3(36, B_), 256, 0, stream>>>(P, G);

    // 4. M[i][j] = sum_k Wq[i,k] G[j,k]  -> fp16 (aliases P region; P dead)
    gemm256x128<1><<<256, 512, 0, stream>>>(
        Wqh, G, nullptr, Mh, D_, D_, D_, D_, 0, MM, MM);

    // 5. scores + softmax (MFMA) -> att fp32
    scores_softmax_mfma<<<B_ * H_, 256, 0, stream>>>(Mh, Wkh, att);

    // 6. T (fp16) -> Th (aliases G; G consumed)
    build_T<<<dim3(D_ / 64, H_, B_), 256, 0, stream>>>(Wv, att, Th);

    // 7. Et[j][i] = sum_k Wo[j][k] T[i][k] -> fp16
    gemm256x128<1><<<256, 512, 0, stream>>>(
        Woh, Th, nullptr, Eth, D_, D_, D_, D_, 0, MM, MM);

    // 8. out[s][j] = sum_i x[s][i] Et[j][i]  -- BK=64 2-slot + setprio (R15)
    gemm256_f16<<<(S_ / 256) * (D_ / 256) * B_, 512, 0, stream>>>(
        xh, Eth, out, D_, D_, D_, D_, (long)S_ * D_, MM, (long)S_ * D_);
}

// Round 22
// 275.363 us; speedup vs baseline: 1.1171x; 1.0803x over previous
//
#include <hip/hip_runtime.h>
#include <hip/hip_bf16.h>

// B=8, S=4096, D=1024, H=16, DH=64.
// R21: fuse scores+softmax+T-build into one kernel (phase-B MFMA PV using
// prepacked WvT fp16 + in-LDS fp16 att^T); removes build_T launch + att
// global round-trip. WvT reuses the freed att buffer (ws total unchanged).
// Rest identical to R20 (best-known): fp16 uniform, fp16 split-K partials,
// final GEMM = R15 BK=64 2-slot (coarse floor 96.6us).

#define B_ 8
#define S_ 4096
#define D_ 1024
#define H_ 16

typedef unsigned short u16;
typedef __attribute__((ext_vector_type(4))) short short4v;
typedef __attribute__((ext_vector_type(8))) _Float16 half8v;
typedef __attribute__((ext_vector_type(4))) float f32x4;

typedef __attribute__((address_space(3))) unsigned lds_u32_t;
typedef const __attribute__((address_space(1))) unsigned glb_u32_t;

__device__ __forceinline__ unsigned short f2h(float f) {
    _Float16 h = (_Float16)f;
    return __builtin_bit_cast(unsigned short, h);
}
__device__ __forceinline__ float h2f(unsigned short s) {
    return (float)__builtin_bit_cast(_Float16, s);
}
__device__ __forceinline__ void gll16(const u16* g, u16* lds) {
    __builtin_amdgcn_global_load_lds((glb_u32_t*)g, (lds_u32_t*)lds, 16, 0, 0);
}
__device__ __forceinline__ void pair_decode(int pair, int& ti, int& tj) {
    ti = (int)((sqrtf(8.f * pair + 1.f) - 1.f) * 0.5f);
    if ((ti + 1) * (ti + 2) / 2 <= pair) ++ti;
    if (ti * (ti + 1) / 2 > pair) --ti;
    tj = pair - ti * (ti + 1) / 2;
}

// ---------------- Gram split-K (m97 structure, fp16 in, fp16 partials out) ----------------
__global__ __launch_bounds__(256) void gram_splitk(
    const u16* __restrict__ xt, u16* __restrict__ P)
{
    __shared__ u16 As[128 * 32];
    __shared__ u16 Bs[128 * 32];

    const int l = ((blockIdx.x & 7) * 144) + (blockIdx.x >> 3);
    const int batch = l / 144;
    const int rem = l - batch * 144;
    const int chunk = rem / 36;
    const int pair = rem - chunk * 36;
    int ti, tj;
    pair_decode(pair, ti, tj);

    const int t = threadIdx.x, lane = t & 63, wave = t >> 6;
    const int wm = (wave >> 1) * 64, wn = (wave & 1) * 64;
    const int fr = lane & 15, kg = lane >> 4;

    const u16* Ag = xt + ((long)batch * D_ + ti * 128) * S_ + chunk * 1024;
    const u16* Bg = xt + ((long)batch * D_ + tj * 128) * S_ + chunk * 1024;

    f32x4 acc[4][4];
#pragma unroll
    for (int i = 0; i < 4; ++i)
#pragma unroll
        for (int j = 0; j < 4; ++j) acc[i][j] = (f32x4){0.f, 0.f, 0.f, 0.f};

    for (int k0 = 0; k0 < 1024; k0 += 32) {
        if (k0) __syncthreads();
#pragma unroll
        for (int r = 0; r < 2; ++r) {
            const int off = r * 2048 + t * 8;
            const int row = off >> 5, kc = off & 31;
            gll16(Ag + (long)row * S_ + k0 + kc, As + off);
            gll16(Bg + (long)row * S_ + k0 + kc, Bs + off);
        }
        __syncthreads();

        const int ao = (wm + fr) * 32 + kg * 8;
        const int bo = (wn + fr) * 32 + kg * 8;
        half8v a[4], b[4];
#pragma unroll
        for (int mt = 0; mt < 4; ++mt) a[mt] = *(const half8v*)&As[ao + mt * 512];
#pragma unroll
        for (int nt = 0; nt < 4; ++nt) b[nt] = *(const half8v*)&Bs[bo + nt * 512];
#pragma unroll
        for (int mt = 0; mt < 4; ++mt)
#pragma unroll
            for (int nt = 0; nt < 4; ++nt)
                acc[mt][nt] = __builtin_amdgcn_mfma_f32_16x16x32_f16(a[mt], b[nt], acc[mt][nt], 0, 0, 0);
    }

    u16* out = P + (((long)chunk * B_ + batch) * 36 + pair) * 16384;
#pragma unroll
    for (int mt = 0; mt < 4; ++mt)
#pragma unroll
        for (int nt = 0; nt < 4; ++nt)
#pragma unroll
            for (int q = 0; q < 4; ++q)
                out[(wm + mt * 16 + kg * 4 + q) * 128 + wn + nt * 16 + fr] = f2h(acc[mt][nt][q]);
}

// ---------------- reduce fp16 partials + mirror (fp16 out) ----------------
__global__ __launch_bounds__(256) void reduce_mirror(
    const u16* __restrict__ P, u16* __restrict__ G)
{
    __shared__ u16 th[128][132];
    const int pair = blockIdx.x, b = blockIdx.y;
    int ti, tj;
    pair_decode(pair, ti, tj);
    const int t = threadIdx.x;
    const long tile = 16384;
    const long cs = (long)B_ * 36 * tile;
    const u16* base = P + ((long)b * 36 + pair) * tile;
    u16* GB = G + (long)b * D_ * D_;

#pragma unroll
    for (int e = 0; e < 16; ++e) {
        const int idx = e * 1024 + t * 4;
        short4v s0 = *(const short4v*)&base[idx];
        short4v s1 = *(const short4v*)&base[cs + idx];
        short4v s2 = *(const short4v*)&base[2 * cs + idx];
        short4v s3 = *(const short4v*)&base[3 * cs + idx];
        const int r = idx >> 7, c = idx & 127;
        short4v hv;
#pragma unroll
        for (int j = 0; j < 4; ++j) {
            const float f = h2f((u16)s0[j]) + h2f((u16)s1[j]) + h2f((u16)s2[j]) + h2f((u16)s3[j]);
            hv[j] = (short)f2h(f);
        }
        *(short4v*)&GB[(long)(ti * 128 + r) * D_ + tj * 128 + c] = hv;
        if (ti != tj) {
#pragma unroll
            for (int j = 0; j < 4; ++j) th[c + j][r] = (u16)hv[j];
        }
    }
    if (ti != tj) {
        __syncthreads();
#pragma unroll
        for (int e = 0; e < 16; ++e) {
            const int idx = e * 1024 + t * 4;
            const int r = idx >> 7, c = idx & 127;
            short4v hv = *(const short4v*)&th[r][c];
            *(short4v*)&GB[(long)(tj * 128 + r) * D_ + ti * 128 + c] = hv;
        }
    }
}

// ---------------- 256x128 3-buf counted-vmcnt GEMM (fp16) ----------------
template<int OUT>
__global__ __launch_bounds__(512) void gemm256x128(
    const u16* __restrict__ A, const u16* __restrict__ B,
    float* __restrict__ Cf, u16* __restrict__ Ch,
    int K, int lda, int ldb, int ldc, long sA, long sB, long sC)
{
    constexpr int BSZ = 12288;
    constexpr int AOF = 0, BOF = 8192;
    __shared__ u16 lds[3 * BSZ];

    const int p = blockIdx.x;
    const int l = (p & 7) * 32 + (p >> 3);
    const int bz = l >> 5;
    const int bm0 = ((l >> 3) & 3) * 256;
    const int bn0 = (l & 7) * 128;

    const int t = threadIdx.x, lane = t & 63, wave = t >> 6;
    const int wm = (wave >> 1) * 64, wn = (wave & 1) * 64;
    const int fr = lane & 15, kg = lane >> 4;
    const int xs = (fr >> 1) & 3;

    const u16* gA = A + (long)bz * sA + (long)bm0 * lda;
    const u16* gB = B + (long)bz * sB + (long)bn0 * ldb;

    f32x4 acc[4][4];
#pragma unroll
    for (int i = 0; i < 4; ++i)
#pragma unroll
        for (int j = 0; j < 4; ++j) acc[i][j] = (f32x4){0.f, 0.f, 0.f, 0.f};

    const int NT = K >> 5;

    auto stage = [&](int tt, int bs) {
        u16* base = &lds[bs * BSZ];
#pragma unroll
        for (int r = 0; r < 2; ++r) {
            const int idx = t + r * 512;
            const int row = idx >> 2, kq = idx & 3;
            const int ks = (kq ^ ((row >> 1) & 3)) << 3;
            gll16(gA + (long)row * lda + tt * 32 + ks, base + AOF + idx * 8);
        }
        {
            const int row = t >> 2, kq = t & 3;
            const int ks = (kq ^ ((row >> 1) & 3)) << 3;
            gll16(gB + (long)row * ldb + tt * 32 + ks, base + BOF + t * 8);
        }
    };

    stage(0, 0);
    stage(1, 1);
    asm volatile("s_waitcnt vmcnt(3)" ::: "memory");
    __builtin_amdgcn_s_barrier();

    for (int tt = 0; tt < NT; ++tt) {
        const u16* base = &lds[(tt % 3) * BSZ];
        if (tt + 2 < NT) stage(tt + 2, (tt + 2) % 3);

        const int ko = (kg ^ xs) << 3;
        half8v a[4], b[4];
#pragma unroll
        for (int mt = 0; mt < 4; ++mt) a[mt] = *(const half8v*)&base[AOF + (wm + mt * 16 + fr) * 32 + ko];
#pragma unroll
        for (int nt = 0; nt < 4; ++nt) b[nt] = *(const half8v*)&base[BOF + (wn + nt * 16 + fr) * 32 + ko];
#pragma unroll
        for (int mt = 0; mt < 4; ++mt)
#pragma unroll
            for (int nt = 0; nt < 4; ++nt)
                acc[mt][nt] = __builtin_amdgcn_mfma_f32_16x16x32_f16(a[mt], b[nt], acc[mt][nt], 0, 0, 0);

        if (tt + 1 < NT) {
            if (tt + 2 < NT) asm volatile("s_waitcnt vmcnt(3)" ::: "memory");
            else             asm volatile("s_waitcnt vmcnt(0)" ::: "memory");
            __builtin_amdgcn_s_barrier();
        }
    }

#pragma unroll
    for (int mt = 0; mt < 4; ++mt)
#pragma unroll
        for (int nt = 0; nt < 4; ++nt)
#pragma unroll
            for (int q = 0; q < 4; ++q) {
                const int row = bm0 + wm + mt * 16 + kg * 4 + q;
                const int col = bn0 + wn + nt * 16 + fr;
                const float v = acc[mt][nt][q];
                const long idx = (long)bz * sC + (long)row * ldc + col;
                if (OUT == 0) Cf[idx] = v;
                else Ch[idx] = f2h(v);
            }
}

// ---------------- fused scores + softmax + T (MFMA both phases) ----------------
// Grid 128 = (b,h), 256 thr (4 waves).
// Phase A: scores[d][e] = (1/8) sum_j M[h64+d][j]*Wk[h64+e][j]; softmax over e;
//          att^T stored fp16 in LDS attT[e][d].
// Phase B: T[i][h64+e] = sum_d WvT[i][h64+d] * attT[e][d]  (M=1024,N=64,K=64),
//          2-slot dbuf staging of WvT i-tiles (128 rows x 64 cols).
__global__ __launch_bounds__(256) void scores_sm_T(
    const u16* __restrict__ M, const u16* __restrict__ Wkh,
    const u16* __restrict__ WvT, u16* __restrict__ T)
{
    constexpr int BSZ = 4096;
    constexpr int AOF = 0, BOF = 2048;
    __shared__ u16 lds[3 * BSZ];          // phase-A staging (24 KB)
    __shared__ float Sm[64][68];
    __shared__ float rowm[64], rowsv[64];
    __shared__ u16 attT[64][72];          // [e][d] fp16 (144B rows: 2-way free)
    __shared__ u16 Av[2][128 * 64];       // phase-B A-tiles (2 x 16 KB)

    const int bh = blockIdx.x;
    const int b = bh >> 4, h = bh & 15;
    const u16* gA = M + (long)b * D_ * D_ + (long)h * 64 * D_;
    const u16* gB = Wkh + (long)h * 64 * D_;

    const int t = threadIdx.x, lane = t & 63, wave = t >> 6;
    const int fr = lane & 15, kg = lane >> 4;
    const int xs = (fr >> 1) & 3;
    const int wrow = wave * 16;

    f32x4 acc[4];
#pragma unroll
    for (int i = 0; i < 4; ++i) acc[i] = (f32x4){0.f, 0.f, 0.f, 0.f};

    auto stage = [&](int tt, int bs) {
        u16* base = &lds[bs * BSZ];
        const int row = t >> 2, kq = t & 3;
        const int ks = (kq ^ ((row >> 1) & 3)) << 3;
        gll16(gA + (long)row * D_ + tt * 32 + ks, base + AOF + t * 8);
        gll16(gB + (long)row * D_ + tt * 32 + ks, base + BOF + t * 8);
    };

    stage(0, 0);
    stage(1, 1);
    asm volatile("s_waitcnt vmcnt(2)" ::: "memory");
    __builtin_amdgcn_s_barrier();

    const int NT = 32;
    for (int tt = 0; tt < NT; ++tt) {
        const u16* base = &lds[(tt % 3) * BSZ];
        if (tt + 2 < NT) stage(tt + 2, (tt + 2) % 3);

        const int ko = (kg ^ xs) << 3;
        half8v a = *(const half8v*)&base[AOF + (wrow + fr) * 32 + ko];
#pragma unroll
        for (int nt = 0; nt < 4; ++nt) {
            half8v bv = *(const half8v*)&base[BOF + (nt * 16 + fr) * 32 + ko];
            acc[nt] = __builtin_amdgcn_mfma_f32_16x16x32_f16(a, bv, acc[nt], 0, 0, 0);
        }

        if (tt + 1 < NT) {
            if (tt + 2 < NT) asm volatile("s_waitcnt vmcnt(2)" ::: "memory");
            else             asm volatile("s_waitcnt vmcnt(0)" ::: "memory");
            __builtin_amdgcn_s_barrier();
        }
    }

#pragma unroll
    for (int nt = 0; nt < 4; ++nt)
#pragma unroll
        for (int q = 0; q < 4; ++q)
            Sm[wrow + kg * 4 + q][nt * 16 + fr] = acc[nt][q] * 0.125f;
    __syncthreads();

    if (t < 64) {
        float m = -1e30f;
        for (int ee = 0; ee < 64; ++ee) m = fmaxf(m, Sm[t][ee]);
        float s = 0.f;
        for (int ee = 0; ee < 64; ++ee) s += expf(Sm[t][ee] - m);
        rowm[t] = m;
        rowsv[t] = 1.0f / s;
    }
    __syncthreads();
    // att^T fp16 into LDS: thread handles (d, e)
#pragma unroll
    for (int dd = 0; dd < 16; ++dd) {
        const int d = (t >> 6) * 16 + dd;
        const int e = t & 63;
        attT[e][d] = f2h(expf(Sm[d][e] - rowm[d]) * rowsv[d]);
    }
    __syncthreads();

    // -------- phase B: T-GEMM (8 i-tiles of 128 rows, 2-slot dbuf) --------
    const u16* gAv = WvT + (long)h * 64;             // row i, 64 cols
    u16* Tb = T + (long)b * D_ * D_ + (long)h * 64;  // col base h*64

    auto stageA = [&](int it, int s) {
#pragma unroll
        for (int r = 0; r < 4; ++r) {
            const int idx = t + r * 256;             // 0..1023 chunks
            const int row = idx >> 3, kq = idx & 7;
            const int ks = (kq ^ ((row >> 1) & 7)) << 3;
            gll16(gAv + (long)(it * 128 + row) * D_ + ks, &Av[s][idx * 8]);
        }
    };

    stageA(0, 0);
    asm volatile("s_waitcnt vmcnt(0)" ::: "memory");
    __builtin_amdgcn_s_barrier();

    for (int it = 0; it < 8; ++it) {
        const int cur = it & 1;
        if (it + 1 < 8) stageA(it + 1, cur ^ 1);

        f32x4 accT[2][4];
#pragma unroll
        for (int m = 0; m < 2; ++m)
#pragma unroll
            for (int nt = 0; nt < 4; ++nt) accT[m][nt] = (f32x4){0.f, 0.f, 0.f, 0.f};

#pragma unroll
        for (int step = 0; step < 2; ++step) {
            const int kq = step * 4 + kg;
            half8v bv[4];
#pragma unroll
            for (int nt = 0; nt < 4; ++nt)
                bv[nt] = *(const half8v*)&attT[nt * 16 + fr][kq * 8];
#pragma unroll
            for (int m = 0; m < 2; ++m) {
                const int rl = wave * 32 + m * 16 + fr;
                half8v av = *(const half8v*)&Av[cur][rl * 64 + ((kq ^ ((rl >> 1) & 7)) << 3)];
#pragma unroll
                for (int nt = 0; nt < 4; ++nt)
                    accT[m][nt] = __builtin_amdgcn_mfma_f32_16x16x32_f16(av, bv[nt], accT[m][nt], 0, 0, 0);
            }
        }

        // write T frags (C/D layout: col=fr, row=kg*4+q)
#pragma unroll
        for (int m = 0; m < 2; ++m)
#pragma unroll
            for (int nt = 0; nt < 4; ++nt)
#pragma unroll
                for (int q = 0; q < 4; ++q) {
                    const int ri = it * 128 + wave * 32 + m * 16 + kg * 4 + q;
                    Tb[(long)ri * D_ + nt * 16 + fr] = f2h(accT[m][nt][q]);
                }

        asm volatile("s_waitcnt vmcnt(0)" ::: "memory");
        __builtin_amdgcn_s_barrier();
    }
}

// ---------------- final GEMM: 256^2, BK=64, 2-slot stage-at-iter-start ----------------
__global__ __launch_bounds__(512) void gemm256_f16(
    const u16* __restrict__ A, const u16* __restrict__ B, float* __restrict__ C,
    int K, int lda, int ldb, int ldc, long sA, long sB, long sC)
{
    __shared__ u16 lds[2][2][256 * 64];   // 128 KiB

    const int p = blockIdx.x;
    const int l = (p & 7) * 64 + (p >> 3);   // one batch per XCD
    const int bz = l >> 6;
    const int bm0 = ((l >> 2) & 15) * 256;
    const int bn0 = (l & 3) * 256;

    const int t = threadIdx.x, lane = t & 63, wave = t >> 6;
    const int wm = (wave >> 2) * 128, wn = (wave & 3) * 64;
    const int fr = lane & 15, kg = lane >> 4;

    const u16* Ag = A + (long)bz * sA + (long)bm0 * lda;
    const u16* Bg = B + (long)bz * sB + (long)bn0 * ldb;

    f32x4 acc[8][4];
#pragma unroll
    for (int i = 0; i < 8; ++i)
#pragma unroll
        for (int j = 0; j < 4; ++j) acc[i][j] = (f32x4){0.f, 0.f, 0.f, 0.f};

    const int NT = K >> 6;   // 16

    auto stage = [&](int tt, int s) {
#pragma unroll
        for (int c = 0; c < 4; ++c) {
            const int idx = t + c * 512;
            const int row = idx >> 3;
            const int kq = idx & 7;
            const int ks = (kq ^ ((row >> 1) & 7)) << 3;
            gll16(Ag + (long)row * lda + tt * 64 + ks, &lds[s][0][idx * 8]);
            gll16(Bg + (long)row * ldb + tt * 64 + ks, &lds[s][1][idx * 8]);
        }
    };

    stage(0, 0);
    asm volatile("s_waitcnt vmcnt(0)" ::: "memory");
    __builtin_amdgcn_s_barrier();

    for (int tt = 0; tt < NT; ++tt) {
        const int cur = tt & 1;
        if (tt + 1 < NT) stage(tt + 1, cur ^ 1);

        const u16* As = &lds[cur][0][0];
        const u16* Bs = &lds[cur][1][0];

        __builtin_amdgcn_s_setprio(1);
#pragma unroll
        for (int ks2 = 0; ks2 < 2; ++ks2) {
            half8v bf[4];
#pragma unroll
            for (int nt = 0; nt < 4; ++nt) {
                const int row = wn + nt * 16 + fr;
                const int off = row * 64 + (((ks2 * 4 + kg) ^ ((row >> 1) & 7)) << 3);
                bf[nt] = *(const half8v*)&Bs[off];
            }
#pragma unroll
            for (int mt = 0; mt < 8; ++mt) {
                const int row = wm + mt * 16 + fr;
                const int off = row * 64 + (((ks2 * 4 + kg) ^ ((row >> 1) & 7)) << 3);
                half8v af = *(const half8v*)&As[off];
#pragma unroll
                for (int nt = 0; nt < 4; ++nt)
                    acc[mt][nt] = __builtin_amdgcn_mfma_f32_16x16x32_f16(af, bf[nt], acc[mt][nt], 0, 0, 0);
            }
        }
        __builtin_amdgcn_s_setprio(0);

        asm volatile("s_waitcnt vmcnt(0)" ::: "memory");
        __builtin_amdgcn_s_barrier();
    }

#pragma unroll
    for (int mt = 0; mt < 8; ++mt)
#pragma unroll
        for (int nt = 0; nt < 4; ++nt)
#pragma unroll
            for (int q = 0; q < 4; ++q) {
                const int row = bm0 + wm + mt * 16 + kg * 4 + q;
                const int col = bn0 + wn + nt * 16 + fr;
                C[(long)bz * sC + (long)row * ldc + col] = acc[mt][nt][q];
            }
}

// ---------------- fused prepack: x tiles + weight converts + WvT (1-D grid) ----------------
// blocks 0..8191:      64x64 x-tile -> xt (transposed) + xh, fp16.
// blocks 8192..11263:  Wq/Wk/Wo fp32 -> fp16 (1024 blocks each).
// blocks 11264..11519: Wv 64x64 tile transpose -> WvT fp16 (WvT[i][d']=Wv[d'][i]).
__global__ __launch_bounds__(256) void prepack_all(
    const float* __restrict__ x, u16* __restrict__ xt, u16* __restrict__ xh,
    const float* __restrict__ Wq, const float* __restrict__ Wk,
    const float* __restrict__ Wo, const float* __restrict__ Wv,
    u16* __restrict__ Wqh, u16* __restrict__ Wkh, u16* __restrict__ Woh,
    u16* __restrict__ WvT)
{
    const int bid = blockIdx.x;
    const int t = threadIdx.x;

    if (bid >= 11264) {   // Wv transpose tiles
        __shared__ float tile[64][65];
        const int wb = bid - 11264;
        const int r0 = (wb >> 4) * 64;   // Wv row block (d')
        const int c0 = (wb & 15) * 64;   // Wv col block (i)
        const int sr = t >> 4, dc = (t & 15) * 4;
#pragma unroll
        for (int r = 0; r < 4; ++r) {
            const int s = sr + r * 16;
            float4 v = *(const float4*)&Wv[(long)(r0 + s) * D_ + c0 + dc];
            tile[dc + 0][s] = v.x;
            tile[dc + 1][s] = v.y;
            tile[dc + 2][s] = v.z;
            tile[dc + 3][s] = v.w;
        }
        __syncthreads();
        const int dr = t >> 4, sc = (t & 15) * 4;
#pragma unroll
        for (int r = 0; r < 4; ++r) {
            const int d = dr + r * 16;
            short4v hv;
#pragma unroll
            for (int j = 0; j < 4; ++j) hv[j] = (short)f2h(tile[d][sc + j]);
            *(short4v*)&WvT[(long)(c0 + d) * D_ + r0 + sc] = hv;
        }
        return;
    }
    if (bid >= 8192) {    // plain weight converts
        const int wb = bid - 8192;
        const float* src;
        u16* dst;
        if (wb < 1024)      { src = Wq; dst = Wqh; }
        else if (wb < 2048) { src = Wk; dst = Wkh; }
        else                { src = Wo; dst = Woh; }
        const long i = ((long)(wb & 1023) * 256 + t) * 4;
        float4 v = *(const float4*)&src[i];
        short4v hv = {(short)f2h(v.x), (short)f2h(v.y), (short)f2h(v.z), (short)f2h(v.w)};
        *(short4v*)&dst[i] = hv;
        return;
    }

    __shared__ float tile[64][65];
    const int d0 = (bid & 15) * 64;
    const int s0 = ((bid >> 4) & 63) * 64;
    const int b = bid >> 10;
    const float* xb = x + (long)b * S_ * D_;
    const int sr = t >> 4, dc = (t & 15) * 4;
#pragma unroll
    for (int r = 0; r < 4; ++r) {
        const int s = sr + r * 16;
        float4 v = *(const float4*)&xb[(long)(s0 + s) * D_ + d0 + dc];
        tile[dc + 0][s] = v.x;
        tile[dc + 1][s] = v.y;
        tile[dc + 2][s] = v.z;
        tile[dc + 3][s] = v.w;
        short4v hv = {(short)f2h(v.x), (short)f2h(v.y), (short)f2h(v.z), (short)f2h(v.w)};
        *(short4v*)&xh[((long)b * S_ + s0 + s) * D_ + d0 + dc] = hv;
    }
    __syncthreads();
    const int dr = t >> 4, sc = (t & 15) * 4;
    u16* tb = xt + (long)b * D_ * S_;
#pragma unroll
    for (int r = 0; r < 4; ++r) {
        const int d = dr + r * 16;
        short4v hv;
#pragma unroll
        for (int j = 0; j < 4; ++j) hv[j] = (short)f2h(tile[d][sc + j]);
        *(short4v*)&tb[(long)(d0 + d) * S_ + s0 + sc] = hv;
    }
}

extern "C" void kernel_launch(void* const* d_in, const int* in_sizes, int n_in,
                              void* d_out, int out_size, void* d_ws, size_t ws_size,
                              hipStream_t stream) {
    const float* x  = (const float*)d_in[0];
    const float* Wq = (const float*)d_in[1];
    const float* Wk = (const float*)d_in[2];
    const float* Wv = (const float*)d_in[3];
    const float* Wo = (const float*)d_in[4];
    float* out = (float*)d_out;

    const long MM = (long)D_ * D_;          // 1,048,576
    const long XE = (long)B_ * S_ * D_;     // 33,554,432
    const long GE = (long)B_ * MM;          // 8,388,608
    const long PB = 4L * B_ * 36 * 16384 * 4;  // region reserved (P fp16 uses half)

    u16* xt = (u16*)d_out;                  // fp16 [B][D][S]; dead before final GEMM

    // ws layout = exactly 184,549,376 B (proven available since R6):
    // xh | P-region (P fp16; M fp16 aliases) | G | Eth | WvT (2MB, was att) |
    // Wqh | Woh | Wkh
    char* w = (char*)d_ws;
    u16* xh    = (u16*)w;   w += XE * 2;
    u16* P     = (u16*)w;
    u16* Mh    = (u16*)w;   w += PB;
    u16* G     = (u16*)w;   w += GE * 2;
    u16* Eth   = (u16*)w;   w += GE * 2;
    u16* WvT   = (u16*)w;   w += MM * 2;    // exactly the old att slot size
    u16* Wqh   = (u16*)w;   w += MM * 2;
    u16* Woh   = (u16*)w;   w += MM * 2;
    u16* Wkh   = (u16*)w;
    u16* Th = G;

    // 1. fused prepack (x tiles + 3 weight converts + WvT transpose)
    prepack_all<<<8192 + 3072 + 256, 256, 0, stream>>>(
        x, xt, xh, Wq, Wk, Wo, Wv, Wqh, Wkh, Woh, WvT);

    // 2. Gram split-K -> P fp16 (m97 structure)
    gram_splitk<<<36 * 4 * B_, 256, 0, stream>>>(xt, P);

    // 3. reduce + mirror -> G fp16
    reduce_mirror<<<dim3(36, B_), 256, 0, stream>>>(P, G);

    // 4. M[i][j] = sum_k Wq[i,k] G[j,k]  -> fp16 (aliases P region; P dead)
    gemm256x128<1><<<256, 512, 0, stream>>>(
        Wqh, G, nullptr, Mh, D_, D_, D_, D_, 0, MM, MM);

    // 5. fused scores + softmax + T  -> Th (aliases G; G consumed by step 4)
    scores_sm_T<<<B_ * H_, 256, 0, stream>>>(Mh, Wkh, WvT, Th);

    // 6. Et[j][i] = sum_k Wo[j][k] T[i][k] -> fp16
    gemm256x128<1><<<256, 512, 0, stream>>>(
        Woh, Th, nullptr, Eth, D_, D_, D_, D_, 0, MM, MM);

    // 7. out[s][j] = sum_i x[s][i] Et[j][i]  -- BK=64 2-slot + setprio (R15)
    gemm256_f16<<<(S_ / 256) * (D_ / 256) * B_, 512, 0, stream>>>(
        xh, Eth, out, D_, D_, D_, D_, (long)S_ * D_, MM, (long)S_ * D_);
}